// Round 1
// baseline (570.593 us; speedup 1.0000x reference)
//
#include <hip/hip_runtime.h>

// CapsuleLinear dynamic routing via bf16 hi/lo MFMA. N=64, I=256, O=128, K=16, L=32.
//
// Round 11 = R10's prep/fragment format + occupancy-repaired main:
//   caps_main was 1 block/CU (grid 256) x 8 waves = 2 waves/SIMD, depth-1
//   prefetch with a vmcnt(0)-forcing register copy each batch -> latency-bound
//   (MfmaUtil 14%, VALUBusy 21%, Occupancy 19.8%). Now: 1024-thread blocks
//   (16 waves = 4 waves/SIMD), 16 i per wave, batch-1 A/B named double-buffer
//   (no C=Nx copies, counted vmcnt), load->use distance ~1 compute phase.
//   Numerics identical to R10 (hi/lo RNE split, 3-MFMA triple product).
// caps_prep: per-wave LDS transpose needs no block barrier -> s_waitcnt only.

#define ICAPS 256
#define OCAPS 128
#define WS_XC 67108864ull
#define WS_NEED 68157440ull
#define KPAD 20

typedef __attribute__((ext_vector_type(8))) short s16x8;
typedef __attribute__((ext_vector_type(16))) float f32x16;

union u4s8 { unsigned u[4]; s16x8 v; };

__device__ inline unsigned rne_adj(unsigned u) {       // bits + RNE increment
    return u + 0x7FFFu + ((u >> 16) & 1u);
}

// RNE hi/lo split of 8 fp32 -> two packed s16x8 (bf16 pairs), R4/R6 numerics.
__device__ inline void split8(const float* f, s16x8& hi, s16x8& lo) {
    u4s8 H, L;
    #pragma unroll
    for (int c = 0; c < 4; ++c) {
        const unsigned u0 = __float_as_uint(f[2 * c]);
        const unsigned u1 = __float_as_uint(f[2 * c + 1]);
        const unsigned r0 = rne_adj(u0), r1 = rne_adj(u1);
        H.u[c] = __builtin_amdgcn_perm(r1, r0, 0x07060302u);   // {hi16(r1),hi16(r0)}
        const float h0 = __uint_as_float(r0 & 0xFFFF0000u);
        const float h1 = __uint_as_float(r1 & 0xFFFF0000u);
        const unsigned l0 = rne_adj(__float_as_uint(f[2 * c] - h0));      // exact resid
        const unsigned l1 = rne_adj(__float_as_uint(f[2 * c + 1] - h1));  // then RNE
        L.u[c] = __builtin_amdgcn_perm(l1, l0, 0x07060302u);
    }
    hi = H.v; lo = L.v;
}

// ---------------- prep: coalesced read + LDS transpose + split ----------------
// w tiles: gid 0..32767 (= o*256+i); x tiles: gid 32768..33279 (= nh*256+i).
__global__ __launch_bounds__(512)
void caps_prep(const float* __restrict__ x, const float* __restrict__ w,
               unsigned char* __restrict__ ws) {
    __shared__ float T[8][32 * KPAD];     // per-wave 2.5 KB transpose buffer
    const int wv = threadIdx.x >> 6, lane = threadIdx.x & 63;
    const int gid = blockIdx.x * 8 + wv;
    float f[8];
    s16x8 hi, lo;

    if (gid < 32768) {
        // coalesced: wave reads its whole 2KB tile (512 floats) contiguously
        const float* src = w + (size_t)gid * 512 + lane * 8;
        const float4 a = *(const float4*)src;
        const float4 b = *(const float4*)(src + 4);
        const float v[8] = {a.x, a.y, a.z, a.w, b.x, b.y, b.z, b.w};
        // element j: k = lane>>2 (const), l = (lane&3)*8 + j  -> T[l][k]
        {
            float* Tw = &T[wv][0];
            const int k = lane >> 2, l0 = (lane & 3) * 8;
            #pragma unroll
            for (int j = 0; j < 8; ++j) Tw[(l0 + j) * KPAD + k] = v[j];
        }
        // T is strictly per-wave: a wave-local LDS drain suffices (no barrier).
        asm volatile("s_waitcnt lgkmcnt(0)" ::: "memory");
        // fragment read: l = lane&31, k = kb..kb+7 (contiguous -> 2x b128)
        {
            const float* rd = &T[wv][(lane & 31) * KPAD + (lane >> 5) * 8];
            const float4 ra = *(const float4*)rd;
            const float4 rb = *(const float4*)(rd + 4);
            f[0] = ra.x; f[1] = ra.y; f[2] = ra.z; f[3] = ra.w;
            f[4] = rb.x; f[5] = rb.y; f[6] = rb.z; f[7] = rb.w;
        }
        split8(f, hi, lo);
        s16x8* WC = (s16x8*)ws;
        WC[(size_t)gid * 128 + lane] = hi;        // 1KB coalesced
        WC[(size_t)gid * 128 + 64 + lane] = lo;   // 1KB coalesced
    } else if (gid < 33280) {
        const int id = gid - 32768;
        const int nh = id >> 8, i = id & 255;
        const int n = lane & 31, kb = (lane >> 5) * 8;
        const float* src = x + ((size_t)(nh * 32 + n) * ICAPS + i) * 16 + kb;
        const float4 a = *(const float4*)src;
        const float4 b = *(const float4*)(src + 4);
        f[0] = a.x; f[1] = a.y; f[2] = a.z; f[3] = a.w;
        f[4] = b.x; f[5] = b.y; f[6] = b.z; f[7] = b.w;
        split8(f, hi, lo);
        s16x8* XC = (s16x8*)(ws + WS_XC);
        XC[(size_t)id * 128 + lane] = hi;
        XC[(size_t)id * 128 + 64 + lane] = lo;
    }
}

// ---------------- main: MFMA routing, 16 waves (4/SIMD), A/B dbuf ----------------

#define MF(a, b, c) __builtin_amdgcn_mfma_f32_32x32x16_bf16(a, b, c, 0, 0, 0)

#define LDFRAG(W0, W1, X0, X1, ii)                   \
    {                                                \
        const size_t b_ = (size_t)(ii) * 128;        \
        W0 = Wp[b_]; W1 = Wp[b_ + 64];               \
        X0 = Xp[b_]; X1 = Xp[b_ + 64];               \
    }

#define SOFTSTEP(P, ii)                                                   \
    {                                                                     \
        float da = P[0] * vr[0], db = P[8] * vr[8];                       \
        _Pragma("unroll")                                                 \
        for (int r = 1; r < 8; ++r) {                                     \
            da = fmaf(P[r], vr[r], da);                                   \
            db = fmaf(P[r + 8], vr[r + 8], db);                           \
        }                                                                 \
        float d = da + db;                                                \
        d += __shfl_xor(d, 32);                /* combine l-halves */     \
        if (pass == 1) {                                                  \
            if (half == 0) lg[(ii) * 32 + n] = d;                         \
        } else {                                                          \
            d += lg[(ii) * 32 + n];                                       \
        }                                                                 \
        const float e = __expf(d);                                        \
        z += e;                                                           \
        _Pragma("unroll")                                                 \
        for (int r = 0; r < 16; ++r) uacc[r] = fmaf(e, P[r], uacc[r]);    \
    }

__global__ __launch_bounds__(1024)
void caps_main(const unsigned char* __restrict__ ws, float* __restrict__ out) {
    __shared__ float lg[ICAPS * 32];      // [i][n] 32 KB
    __shared__ float slab[16 * 1280];     // per-wave u partials (lane stride 20), 80 KB
    __shared__ float svv[32 * 33];        // s then v
    __shared__ float zz[16 * 32];
    __shared__ float zinv[32];

    const int t = threadIdx.x, wv = t >> 6, lane = t & 63;
    const int o = blockIdx.x & 127, nh = blockIdx.x >> 7;   // o-pairs share an XCD
    const int n = lane & 31, half = lane >> 5;

    // block layout: per tile 128 s16x8 records; hi at +lane, lo at +64+lane
    const s16x8* Wp = (const s16x8*)ws + (size_t)o * ICAPS * 128 + lane;
    const s16x8* Xp = (const s16x8*)(ws + WS_XC) + (size_t)nh * ICAPS * 128 + lane;

    float vr[16];
    const int ibase = wv * 16;            // 16 i per wave, 16 waves cover 256

    for (int pass = 0; pass < 3; ++pass) {
        float uacc[16];
        #pragma unroll
        for (int r = 0; r < 16; ++r) uacc[r] = 0.f;
        float z = 0.f;

        // batch-1 A/B double buffer: 8 s16x8 = 32 VGPRs total, no copies
        s16x8 Aw0, Aw1, Ax0, Ax1, Bw0, Bw1, Bx0, Bx1;
        LDFRAG(Aw0, Aw1, Ax0, Ax1, ibase);

        if (pass == 0) {
            f32x16 Pa = {}, Pb = {};
            for (int q = 0; q < 8; ++q) {
                const int iA = ibase + 2 * q;
                LDFRAG(Bw0, Bw1, Bx0, Bx1, iA + 1);
                Pa = MF(Aw1, Ax0, Pa);
                Pa = MF(Aw0, Ax1, Pa);
                Pa = MF(Aw0, Ax0, Pa);
                if (q < 7) LDFRAG(Aw0, Aw1, Ax0, Ax1, iA + 2);
                Pb = MF(Bw1, Bx0, Pb);
                Pb = MF(Bw0, Bx1, Pb);
                Pb = MF(Bw0, Bx0, Pb);
            }
            #pragma unroll
            for (int r = 0; r < 16; ++r) uacc[r] = Pa[r] + Pb[r];
        } else {
            for (int q = 0; q < 8; ++q) {
                const int iA = ibase + 2 * q;
                LDFRAG(Bw0, Bw1, Bx0, Bx1, iA + 1);
                f32x16 P0 = {};
                P0 = MF(Aw1, Ax0, P0);
                P0 = MF(Aw0, Ax1, P0);
                P0 = MF(Aw0, Ax0, P0);
                SOFTSTEP(P0, iA);                       // covers B load latency
                if (q < 7) LDFRAG(Aw0, Aw1, Ax0, Ax1, iA + 2);
                f32x16 P1 = {};
                P1 = MF(Bw1, Bx0, P1);
                P1 = MF(Bw0, Bx1, P1);
                P1 = MF(Bw0, Bx0, P1);
                SOFTSTEP(P1, iA + 1);                   // covers A load latency
            }
        }

        // ---- cross-wave reduce of u (and z) over 16 waves ----
        #pragma unroll
        for (int c = 0; c < 4; ++c)
            *(float4*)(&slab[wv * 1280 + lane * 20 + c * 4]) =
                make_float4(uacc[4 * c], uacc[4 * c + 1], uacc[4 * c + 2], uacc[4 * c + 3]);
        if (pass > 0 && half == 0) zz[wv * 32 + n] = z;
        __syncthreads();

        {
            const int lw = t >> 4, r = t & 15;          // 1024 threads -> 1 elem each
            float s = 0.f;
            #pragma unroll
            for (int w8 = 0; w8 < 16; ++w8) s += slab[w8 * 1280 + lw * 20 + r];
            const int nn = lw & 31, ll = (r & 3) + 8 * (r >> 2) + 4 * (lw >> 5);
            svv[nn * 33 + ll] = s;
        }
        if (t < 32) {
            if (pass == 0) zinv[t] = 1.0f / 256.0f;
            else {
                float zs = 0.f;
                #pragma unroll
                for (int w8 = 0; w8 < 16; ++w8) zs += zz[w8 * 32 + t];
                zinv[t] = 1.0f / zs;
            }
        }
        __syncthreads();

        // ---- squash (and output on last pass) ----
        if (t < 512) {
            const int nq = t >> 4, sub = t & 15;
            const float a = svv[nq * 33 + sub] * zinv[nq];
            const float b = svv[nq * 33 + sub + 16] * zinv[nq];
            float sq = a * a + b * b;
            #pragma unroll
            for (int m = 1; m < 16; m <<= 1) sq += __shfl_xor(sq, m, 16);
            const float sc = sqrtf(sq) / (1.0f + sq);
            if (pass == 2) {
                const int ng = nh * 32 + nq;
                out[((size_t)ng * OCAPS + o) * 32 + sub] = a * sc;
                out[((size_t)ng * OCAPS + o) * 32 + sub + 16] = b * sc;
            } else {
                svv[nq * 33 + sub] = a * sc;
                svv[nq * 33 + sub + 16] = b * sc;
            }
        }
        if (pass < 2) {
            __syncthreads();
            #pragma unroll
            for (int r = 0; r < 16; ++r) {
                const int l = (r & 3) + 8 * (r >> 2) + 4 * half;
                vr[r] = svv[n * 33 + l];
            }
        }
    }
}

// ---------------- fallback (round-3 kernel, no ws needed) ----------------
#define KLEN  16
#define LLEN  32
#define TN    16
#define LGS   257
#define XROW  20
#define XIST  (TN * XROW + 4)
#define SVS   33
#define RBS   33
#define NSTG  32
#define NSTEP (ICAPS / NSTG)

__global__ __launch_bounds__(512, 2)
void caps_route_fb(const float* __restrict__ xg_all,
                   const float* __restrict__ wg_all,
                   float* __restrict__ out) {
    __shared__ float lg[TN * LGS];
    __shared__ float xt[NSTG * XIST];
    __shared__ float sv[TN * SVS];
    __shared__ float zz[8][TN];
    __shared__ float zinv[TN];

    const int t   = threadIdx.x;
    const int o   = blockIdx.x & 127;
    const int n0  = (blockIdx.x >> 7) * TN;
    const int isp = t >> 4;
    const int lb  = (t >> 2) & 3;
    const int nb  = t & 3;
    const int l0  = lb * 8;

    const float* xg = xg_all + (size_t)n0 * ICAPS * KLEN;
    const float* wg = wg_all + (size_t)o * ICAPS * KLEN * LLEN;

    for (int pass = 0; pass < 3; ++pass) {
        float u[4][8];
        float zq[4] = {0.f, 0.f, 0.f, 0.f};
        #pragma unroll
        for (int q = 0; q < 4; ++q)
            #pragma unroll
            for (int r = 0; r < 8; ++r) u[q][r] = 0.f;

        for (int st = 0; st < NSTEP; ++st) {
            const int i0 = st * NSTG;
            __syncthreads();
            #pragma unroll
            for (int j = 0; j < 4; ++j) {
                const int g   = j * 512 + t;
                const int nn  = g >> 7;
                const int rem = g & 127;
                const int il  = rem >> 2;
                const int k4c = rem & 3;
                *(float4*)(&xt[il * XIST + nn * XROW + k4c * 4]) =
                    *(const float4*)(xg + (size_t)(nn * ICAPS + i0 + il) * KLEN + k4c * 4);
            }
            __syncthreads();

            const int i = i0 + isp;
            const float* wp = wg + (size_t)i * (KLEN * LLEN) + l0;
            const float* xp = &xt[isp * XIST];
            float P[4][8];
            #pragma unroll
            for (int q = 0; q < 4; ++q)
                #pragma unroll
                for (int r = 0; r < 8; ++r) P[q][r] = 0.f;

            #pragma unroll
            for (int k4 = 0; k4 < 4; ++k4) {
                float xq[4][4];
                #pragma unroll
                for (int q = 0; q < 4; ++q)
                    *(float4*)(&xq[q][0]) = *(const float4*)(xp + (nb + 4 * q) * XROW + k4 * 4);
                #pragma unroll
                for (int kk = 0; kk < 4; ++kk) {
                    const int k = k4 * 4 + kk;
                    const float4 wa = *(const float4*)(wp + k * LLEN);
                    const float4 wb = *(const float4*)(wp + k * LLEN + 4);
                    #pragma unroll
                    for (int q = 0; q < 4; ++q) {
                        const float xv = xq[q][kk];
                        P[q][0] = fmaf(xv, wa.x, P[q][0]);
                        P[q][1] = fmaf(xv, wa.y, P[q][1]);
                        P[q][2] = fmaf(xv, wa.z, P[q][2]);
                        P[q][3] = fmaf(xv, wa.w, P[q][3]);
                        P[q][4] = fmaf(xv, wb.x, P[q][4]);
                        P[q][5] = fmaf(xv, wb.y, P[q][5]);
                        P[q][6] = fmaf(xv, wb.z, P[q][6]);
                        P[q][7] = fmaf(xv, wb.w, P[q][7]);
                    }
                }
            }

            if (pass == 0) {
                #pragma unroll
                for (int q = 0; q < 4; ++q)
                    #pragma unroll
                    for (int r = 0; r < 8; ++r) u[q][r] += P[q][r];
            } else {
                #pragma unroll
                for (int q = 0; q < 4; ++q) {
                    const float* vp = &sv[(nb + 4 * q) * SVS + l0];
                    float d = P[q][0] * vp[0] + P[q][1] * vp[1] + P[q][2] * vp[2] + P[q][3] * vp[3]
                            + P[q][4] * vp[4] + P[q][5] * vp[5] + P[q][6] * vp[6] + P[q][7] * vp[7];
                    d += __shfl_xor(d, 4);
                    d += __shfl_xor(d, 8);
                    float lnew = d;
                    if (pass == 2) lnew += lg[(nb + 4 * q) * LGS + i];
                    else if (lb == 0) lg[(nb + 4 * q) * LGS + i] = lnew;
                    const float e = __expf(lnew);
                    zq[q] += e;
                    #pragma unroll
                    for (int r = 0; r < 8; ++r) u[q][r] = fmaf(e, P[q][r], u[q][r]);
                }
            }
        }

        #pragma unroll
        for (int q = 0; q < 4; ++q) {
            #pragma unroll
            for (int r = 0; r < 8; ++r) {
                float v = u[q][r];
                v += __shfl_xor(v, 16);
                v += __shfl_xor(v, 32);
                u[q][r] = v;
            }
            float zv = zq[q];
            zv += __shfl_xor(zv, 16);
            zv += __shfl_xor(zv, 32);
            zq[q] = zv;
        }
        __syncthreads();
        {
            const int wvv = t >> 6, lane = t & 63;
            if (lane < 16) {
                float* rb = &xt[wvv * (16 * RBS) + lane * RBS];
                #pragma unroll
                for (int q = 0; q < 4; ++q)
                    #pragma unroll
                    for (int r = 0; r < 8; ++r) rb[q * 8 + r] = u[q][r];
            }
            if (pass > 0 && lane < 4) {
                #pragma unroll
                for (int q = 0; q < 4; ++q) zz[wvv][lane + 4 * q] = zq[q];
            }
        }
        __syncthreads();
        {
            const int low4 = t >> 5, qr = t & 31;
            const int qq = qr >> 3, rr = qr & 7;
            const int lbb = low4 >> 2, nbb = low4 & 3;
            float ssum = 0.f;
            #pragma unroll
            for (int w8 = 0; w8 < 8; ++w8) ssum += xt[w8 * (16 * RBS) + low4 * RBS + qr];
            sv[(nbb + 4 * qq) * SVS + lbb * 8 + rr] = ssum;
        }
        if (t < TN) {
            if (pass == 0) zinv[t] = 1.0f / 256.0f;
            else {
                float zs = 0.f;
                #pragma unroll
                for (int w8 = 0; w8 < 8; ++w8) zs += zz[w8][t];
                zinv[t] = 1.0f / zs;
            }
        }
        __syncthreads();
        {
            const int nn = t >> 5, l = t & 31;
            const float val = sv[nn * SVS + l] * zinv[nn];
            float sq = val * val;
            #pragma unroll
            for (int m = 1; m < 32; m <<= 1) sq += __shfl_xor(sq, m, 32);
            const float sc = sqrtf(sq) / (1.0f + sq);
            if (pass == 2)
                out[((size_t)(n0 + nn) * OCAPS + o) * LLEN + l] = val * sc;
            else
                sv[nn * SVS + l] = val * sc;
        }
    }
}

extern "C" void kernel_launch(void* const* d_in, const int* in_sizes, int n_in,
                              void* d_out, int out_size, void* d_ws, size_t ws_size,
                              hipStream_t stream) {
    const float* x = (const float*)d_in[0];   // [64,256,16]
    const float* w = (const float*)d_in[1];   // [128,256,16,32]
    float* outp = (float*)d_out;              // [64,128,32]
    if (ws_size >= WS_NEED) {
        caps_prep<<<dim3(4160), dim3(512), 0, stream>>>(x, w, (unsigned char*)d_ws);
        caps_main<<<dim3(256), dim3(1024), 0, stream>>>((const unsigned char*)d_ws, outp);
    } else {
        caps_route_fb<<<dim3(512), dim3(512), 0, stream>>>(x, w, outp);
    }
}

// Round 2
// 544.289 us; speedup vs baseline: 1.0483x; 1.0483x over previous
//
#include <hip/hip_runtime.h>

// CapsuleLinear dynamic routing via bf16 hi/lo MFMA. N=64, I=256, O=128, K=16, L=32.
//
// Round 12 = R10's proven 512-thread caps_main + deep rotating prefetch:
//   R11's 1024-thread occupancy fix spilled (VGPR capped 64, 760MB scratch
//   writes, 514us). Occupancy is grid-pinned (256 blocks = 1/CU), so attack
//   latency with MLP instead: replace the batch-2 ping-pong (copy forces a
//   vmcnt drain each batch, ~230cy cover vs ~650cy LLC latency) with a
//   3-buffer rotating pipeline (6 i-tiles = 24KB/wave in flight, no copies).
//   Numerics identical to R10 (hi/lo RNE split, 3-MFMA triple product).
// caps_prep: unchanged from R10 except per-wave transpose uses a wave-local
//   lgkmcnt drain instead of a block barrier (verified in R11 run).

#define ICAPS 256
#define OCAPS 128
#define WS_XC 67108864ull
#define WS_NEED 68157440ull
#define KPAD 20

typedef __attribute__((ext_vector_type(8))) short s16x8;
typedef __attribute__((ext_vector_type(16))) float f32x16;

union u4s8 { unsigned u[4]; s16x8 v; };

__device__ inline unsigned rne_adj(unsigned u) {       // bits + RNE increment
    return u + 0x7FFFu + ((u >> 16) & 1u);
}

// RNE hi/lo split of 8 fp32 -> two packed s16x8 (bf16 pairs), R4/R6 numerics.
__device__ inline void split8(const float* f, s16x8& hi, s16x8& lo) {
    u4s8 H, L;
    #pragma unroll
    for (int c = 0; c < 4; ++c) {
        const unsigned u0 = __float_as_uint(f[2 * c]);
        const unsigned u1 = __float_as_uint(f[2 * c + 1]);
        const unsigned r0 = rne_adj(u0), r1 = rne_adj(u1);
        H.u[c] = __builtin_amdgcn_perm(r1, r0, 0x07060302u);   // {hi16(r1),hi16(r0)}
        const float h0 = __uint_as_float(r0 & 0xFFFF0000u);
        const float h1 = __uint_as_float(r1 & 0xFFFF0000u);
        const unsigned l0 = rne_adj(__float_as_uint(f[2 * c] - h0));      // exact resid
        const unsigned l1 = rne_adj(__float_as_uint(f[2 * c + 1] - h1));  // then RNE
        L.u[c] = __builtin_amdgcn_perm(l1, l0, 0x07060302u);
    }
    hi = H.v; lo = L.v;
}

// ---------------- prep: coalesced read + LDS transpose + split ----------------
// w tiles: gid 0..32767 (= o*256+i); x tiles: gid 32768..33279 (= nh*256+i).
__global__ __launch_bounds__(512)
void caps_prep(const float* __restrict__ x, const float* __restrict__ w,
               unsigned char* __restrict__ ws) {
    __shared__ float T[8][32 * KPAD];     // per-wave 2.5 KB transpose buffer
    const int wv = threadIdx.x >> 6, lane = threadIdx.x & 63;
    const int gid = blockIdx.x * 8 + wv;
    float f[8];
    s16x8 hi, lo;

    if (gid < 32768) {
        // coalesced: wave reads its whole 2KB tile (512 floats) contiguously
        const float* src = w + (size_t)gid * 512 + lane * 8;
        const float4 a = *(const float4*)src;
        const float4 b = *(const float4*)(src + 4);
        const float v[8] = {a.x, a.y, a.z, a.w, b.x, b.y, b.z, b.w};
        // element j: k = lane>>2 (const), l = (lane&3)*8 + j  -> T[l][k]
        {
            float* Tw = &T[wv][0];
            const int k = lane >> 2, l0 = (lane & 3) * 8;
            #pragma unroll
            for (int j = 0; j < 8; ++j) Tw[(l0 + j) * KPAD + k] = v[j];
        }
        // T is strictly per-wave: a wave-local LDS drain suffices (no barrier).
        asm volatile("s_waitcnt lgkmcnt(0)" ::: "memory");
        // fragment read: l = lane&31, k = kb..kb+7 (contiguous -> 2x b128)
        {
            const float* rd = &T[wv][(lane & 31) * KPAD + (lane >> 5) * 8];
            const float4 ra = *(const float4*)rd;
            const float4 rb = *(const float4*)(rd + 4);
            f[0] = ra.x; f[1] = ra.y; f[2] = ra.z; f[3] = ra.w;
            f[4] = rb.x; f[5] = rb.y; f[6] = rb.z; f[7] = rb.w;
        }
        split8(f, hi, lo);
        s16x8* WC = (s16x8*)ws;
        WC[(size_t)gid * 128 + lane] = hi;        // 1KB coalesced
        WC[(size_t)gid * 128 + 64 + lane] = lo;   // 1KB coalesced
    } else if (gid < 33280) {
        const int id = gid - 32768;
        const int nh = id >> 8, i = id & 255;
        const int n = lane & 31, kb = (lane >> 5) * 8;
        const float* src = x + ((size_t)(nh * 32 + n) * ICAPS + i) * 16 + kb;
        const float4 a = *(const float4*)src;
        const float4 b = *(const float4*)(src + 4);
        f[0] = a.x; f[1] = a.y; f[2] = a.z; f[3] = a.w;
        f[4] = b.x; f[5] = b.y; f[6] = b.z; f[7] = b.w;
        split8(f, hi, lo);
        s16x8* XC = (s16x8*)(ws + WS_XC);
        XC[(size_t)id * 128 + lane] = hi;
        XC[(size_t)id * 128 + 64 + lane] = lo;
    }
}

// ---------------- main: MFMA routing, 8 waves, 3-buffer rotating prefetch ----------------

#define MF(a, b, c) __builtin_amdgcn_mfma_f32_32x32x16_bf16(a, b, c, 0, 0, 0)

// load one 2-i batch (8 s16x8 = 32 VGPR) for batch index bb (i = ibase+2*bb)
#define LD8(B, bb)                                        \
    {                                                     \
        const size_t b_ = (size_t)(ibase + 2 * (bb)) * 128; \
        B[0] = Wp[b_];       B[1] = Wp[b_ + 64];          \
        B[2] = Xp[b_];       B[3] = Xp[b_ + 64];          \
        B[4] = Wp[b_ + 128]; B[5] = Wp[b_ + 192];         \
        B[6] = Xp[b_ + 128]; B[7] = Xp[b_ + 192];         \
    }

#define SOFTSTEP(P, ii)                                                   \
    {                                                                     \
        float da = P[0] * vr[0], db = P[8] * vr[8];                       \
        _Pragma("unroll")                                                 \
        for (int r = 1; r < 8; ++r) {                                     \
            da = fmaf(P[r], vr[r], da);                                   \
            db = fmaf(P[r + 8], vr[r + 8], db);                           \
        }                                                                 \
        float d = da + db;                                                \
        d += __shfl_xor(d, 32);                /* combine l-halves */     \
        if (pass == 1) {                                                  \
            if (half == 0) lg[(ii) * 32 + n] = d;                         \
        } else {                                                          \
            d += lg[(ii) * 32 + n];                                       \
        }                                                                 \
        const float e = __expf(d);                                        \
        z += e;                                                           \
        _Pragma("unroll")                                                 \
        for (int r = 0; r < 16; ++r) uacc[r] = fmaf(e, P[r], uacc[r]);    \
    }

__global__ __launch_bounds__(512)
void caps_main(const unsigned char* __restrict__ ws, float* __restrict__ out) {
    __shared__ float lg[ICAPS * 32];      // [i][n] 32 KB
    __shared__ float slab[8 * 1280];      // per-wave u partials (lane stride 20)
    __shared__ float svv[32 * 33];        // s then v
    __shared__ float zz[8 * 32];
    __shared__ float zinv[32];

    const int t = threadIdx.x, wv = t >> 6, lane = t & 63;
    const int o = blockIdx.x & 127, nh = blockIdx.x >> 7;   // o-pairs share an XCD
    const int n = lane & 31, half = lane >> 5;

    // block layout: per tile 128 s16x8 records; hi at +lane, lo at +64+lane
    const s16x8* Wp = (const s16x8*)ws + (size_t)o * ICAPS * 128 + lane;
    const s16x8* Xp = (const s16x8*)(ws + WS_XC) + (size_t)nh * ICAPS * 128 + lane;

    float vr[16];
    const int ibase = wv * 32;            // 32 i per wave, 16 batches of 2

    for (int pass = 0; pass < 3; ++pass) {
        float uacc[16];
        #pragma unroll
        for (int r = 0; r < 16; ++r) uacc[r] = 0.f;
        float z = 0.f;

        // 3-slot rotating batch buffers: 6 i-tiles (24KB/wave) in flight,
        // no register copies, prefetch distance 3 batches.
        s16x8 B[3][8];
        LD8(B[0], 0);
        LD8(B[1], 1);
        LD8(B[2], 2);

        if (pass == 0) {
            f32x16 Pa = {}, Pb = {};
            #pragma unroll
            for (int qq = 0; qq < 16; ++qq) {
                s16x8(&C)[8] = B[qq % 3];             // constant after unroll
                Pa = MF(C[1], C[2], Pa);
                Pb = MF(C[5], C[6], Pb);
                Pa = MF(C[0], C[3], Pa);
                Pb = MF(C[4], C[7], Pb);
                Pa = MF(C[0], C[2], Pa);
                Pb = MF(C[4], C[6], Pb);
                if (qq < 13) LD8(C, qq + 3);
            }
            #pragma unroll
            for (int r = 0; r < 16; ++r) uacc[r] = Pa[r] + Pb[r];
        } else {
            #pragma unroll
            for (int qq = 0; qq < 16; ++qq) {
                s16x8(&C)[8] = B[qq % 3];             // constant after unroll
                f32x16 P0 = {}, P1 = {};
                P0 = MF(C[1], C[2], P0);
                P1 = MF(C[5], C[6], P1);
                P0 = MF(C[0], C[3], P0);
                P1 = MF(C[4], C[7], P1);
                P0 = MF(C[0], C[2], P0);
                P1 = MF(C[4], C[6], P1);
                if (qq < 13) LD8(C, qq + 3);          // loads hide under softmax
                SOFTSTEP(P0, ibase + 2 * qq);
                SOFTSTEP(P1, ibase + 2 * qq + 1);
            }
        }

        // ---- cross-wave reduce of u (and z) over 8 waves ----
        #pragma unroll
        for (int c = 0; c < 4; ++c)
            *(float4*)(&slab[wv * 1280 + lane * 20 + c * 4]) =
                make_float4(uacc[4 * c], uacc[4 * c + 1], uacc[4 * c + 2], uacc[4 * c + 3]);
        if (pass > 0 && half == 0) zz[wv * 32 + n] = z;
        __syncthreads();

        #pragma unroll
        for (int hh = 0; hh < 2; ++hh) {
            const int e = t + hh * 512;
            const int lw = e >> 4, r = e & 15;
            float s = 0.f;
            #pragma unroll
            for (int w8 = 0; w8 < 8; ++w8) s += slab[w8 * 1280 + lw * 20 + r];
            const int nn = lw & 31, ll = (r & 3) + 8 * (r >> 2) + 4 * (lw >> 5);
            svv[nn * 33 + ll] = s;
        }
        if (t < 32) {
            if (pass == 0) zinv[t] = 1.0f / 256.0f;
            else {
                float zs = 0.f;
                #pragma unroll
                for (int w8 = 0; w8 < 8; ++w8) zs += zz[w8 * 32 + t];
                zinv[t] = 1.0f / zs;
            }
        }
        __syncthreads();

        // ---- squash (and output on last pass) ----
        {
            const int nq = t >> 4, sub = t & 15;
            const float a = svv[nq * 33 + sub] * zinv[nq];
            const float b = svv[nq * 33 + sub + 16] * zinv[nq];
            float sq = a * a + b * b;
            #pragma unroll
            for (int m = 1; m < 16; m <<= 1) sq += __shfl_xor(sq, m, 16);
            const float sc = sqrtf(sq) / (1.0f + sq);
            if (pass == 2) {
                const int ng = nh * 32 + nq;
                out[((size_t)ng * OCAPS + o) * 32 + sub] = a * sc;
                out[((size_t)ng * OCAPS + o) * 32 + sub + 16] = b * sc;
            } else {
                svv[nq * 33 + sub] = a * sc;
                svv[nq * 33 + sub + 16] = b * sc;
            }
        }
        if (pass < 2) {
            __syncthreads();
            #pragma unroll
            for (int r = 0; r < 16; ++r) {
                const int l = (r & 3) + 8 * (r >> 2) + 4 * half;
                vr[r] = svv[n * 33 + l];
            }
        }
    }
}

// ---------------- fallback (round-3 kernel, no ws needed) ----------------
#define KLEN  16
#define LLEN  32
#define TN    16
#define LGS   257
#define XROW  20
#define XIST  (TN * XROW + 4)
#define SVS   33
#define RBS   33
#define NSTG  32
#define NSTEP (ICAPS / NSTG)

__global__ __launch_bounds__(512, 2)
void caps_route_fb(const float* __restrict__ xg_all,
                   const float* __restrict__ wg_all,
                   float* __restrict__ out) {
    __shared__ float lg[TN * LGS];
    __shared__ float xt[NSTG * XIST];
    __shared__ float sv[TN * SVS];
    __shared__ float zz[8][TN];
    __shared__ float zinv[TN];

    const int t   = threadIdx.x;
    const int o   = blockIdx.x & 127;
    const int n0  = (blockIdx.x >> 7) * TN;
    const int isp = t >> 4;
    const int lb  = (t >> 2) & 3;
    const int nb  = t & 3;
    const int l0  = lb * 8;

    const float* xg = xg_all + (size_t)n0 * ICAPS * KLEN;
    const float* wg = wg_all + (size_t)o * ICAPS * KLEN * LLEN;

    for (int pass = 0; pass < 3; ++pass) {
        float u[4][8];
        float zq[4] = {0.f, 0.f, 0.f, 0.f};
        #pragma unroll
        for (int q = 0; q < 4; ++q)
            #pragma unroll
            for (int r = 0; r < 8; ++r) u[q][r] = 0.f;

        for (int st = 0; st < NSTEP; ++st) {
            const int i0 = st * NSTG;
            __syncthreads();
            #pragma unroll
            for (int j = 0; j < 4; ++j) {
                const int g   = j * 512 + t;
                const int nn  = g >> 7;
                const int rem = g & 127;
                const int il  = rem >> 2;
                const int k4c = rem & 3;
                *(float4*)(&xt[il * XIST + nn * XROW + k4c * 4]) =
                    *(const float4*)(xg + (size_t)(nn * ICAPS + i0 + il) * KLEN + k4c * 4);
            }
            __syncthreads();

            const int i = i0 + isp;
            const float* wp = wg + (size_t)i * (KLEN * LLEN) + l0;
            const float* xp = &xt[isp * XIST];
            float P[4][8];
            #pragma unroll
            for (int q = 0; q < 4; ++q)
                #pragma unroll
                for (int r = 0; r < 8; ++r) P[q][r] = 0.f;

            #pragma unroll
            for (int k4 = 0; k4 < 4; ++k4) {
                float xq[4][4];
                #pragma unroll
                for (int q = 0; q < 4; ++q)
                    *(float4*)(&xq[q][0]) = *(const float4*)(xp + (nb + 4 * q) * XROW + k4 * 4);
                #pragma unroll
                for (int kk = 0; kk < 4; ++kk) {
                    const int k = k4 * 4 + kk;
                    const float4 wa = *(const float4*)(wp + k * LLEN);
                    const float4 wb = *(const float4*)(wp + k * LLEN + 4);
                    #pragma unroll
                    for (int q = 0; q < 4; ++q) {
                        const float xv = xq[q][kk];
                        P[q][0] = fmaf(xv, wa.x, P[q][0]);
                        P[q][1] = fmaf(xv, wa.y, P[q][1]);
                        P[q][2] = fmaf(xv, wa.z, P[q][2]);
                        P[q][3] = fmaf(xv, wa.w, P[q][3]);
                        P[q][4] = fmaf(xv, wb.x, P[q][4]);
                        P[q][5] = fmaf(xv, wb.y, P[q][5]);
                        P[q][6] = fmaf(xv, wb.z, P[q][6]);
                        P[q][7] = fmaf(xv, wb.w, P[q][7]);
                    }
                }
            }

            if (pass == 0) {
                #pragma unroll
                for (int q = 0; q < 4; ++q)
                    #pragma unroll
                    for (int r = 0; r < 8; ++r) u[q][r] += P[q][r];
            } else {
                #pragma unroll
                for (int q = 0; q < 4; ++q) {
                    const float* vp = &sv[(nb + 4 * q) * SVS + l0];
                    float d = P[q][0] * vp[0] + P[q][1] * vp[1] + P[q][2] * vp[2] + P[q][3] * vp[3]
                            + P[q][4] * vp[4] + P[q][5] * vp[5] + P[q][6] * vp[6] + P[q][7] * vp[7];
                    d += __shfl_xor(d, 4);
                    d += __shfl_xor(d, 8);
                    float lnew = d;
                    if (pass == 2) lnew += lg[(nb + 4 * q) * LGS + i];
                    else if (lb == 0) lg[(nb + 4 * q) * LGS + i] = lnew;
                    const float e = __expf(lnew);
                    zq[q] += e;
                    #pragma unroll
                    for (int r = 0; r < 8; ++r) u[q][r] = fmaf(e, P[q][r], u[q][r]);
                }
            }
        }

        #pragma unroll
        for (int q = 0; q < 4; ++q) {
            #pragma unroll
            for (int r = 0; r < 8; ++r) {
                float v = u[q][r];
                v += __shfl_xor(v, 16);
                v += __shfl_xor(v, 32);
                u[q][r] = v;
            }
            float zv = zq[q];
            zv += __shfl_xor(zv, 16);
            zv += __shfl_xor(zv, 32);
            zq[q] = zv;
        }
        __syncthreads();
        {
            const int wvv = t >> 6, lane = t & 63;
            if (lane < 16) {
                float* rb = &xt[wvv * (16 * RBS) + lane * RBS];
                #pragma unroll
                for (int q = 0; q < 4; ++q)
                    #pragma unroll
                    for (int r = 0; r < 8; ++r) rb[q * 8 + r] = u[q][r];
            }
            if (pass > 0 && lane < 4) {
                #pragma unroll
                for (int q = 0; q < 4; ++q) zz[wvv][lane + 4 * q] = zq[q];
            }
        }
        __syncthreads();
        {
            const int low4 = t >> 5, qr = t & 31;
            const int qq = qr >> 3, rr = qr & 7;
            const int lbb = low4 >> 2, nbb = low4 & 3;
            float ssum = 0.f;
            #pragma unroll
            for (int w8 = 0; w8 < 8; ++w8) ssum += xt[w8 * (16 * RBS) + low4 * RBS + qr];
            sv[(nbb + 4 * qq) * SVS + lbb * 8 + rr] = ssum;
        }
        if (t < TN) {
            if (pass == 0) zinv[t] = 1.0f / 256.0f;
            else {
                float zs = 0.f;
                #pragma unroll
                for (int w8 = 0; w8 < 8; ++w8) zs += zz[w8][t];
                zinv[t] = 1.0f / zs;
            }
        }
        __syncthreads();
        {
            const int nn = t >> 5, l = t & 31;
            const float val = sv[nn * SVS + l] * zinv[nn];
            float sq = val * val;
            #pragma unroll
            for (int m = 1; m < 32; m <<= 1) sq += __shfl_xor(sq, m, 32);
            const float sc = sqrtf(sq) / (1.0f + sq);
            if (pass == 2)
                out[((size_t)(n0 + nn) * OCAPS + o) * LLEN + l] = val * sc;
            else
                sv[nn * SVS + l] = val * sc;
        }
    }
}

extern "C" void kernel_launch(void* const* d_in, const int* in_sizes, int n_in,
                              void* d_out, int out_size, void* d_ws, size_t ws_size,
                              hipStream_t stream) {
    const float* x = (const float*)d_in[0];   // [64,256,16]
    const float* w = (const float*)d_in[1];   // [128,256,16,32]
    float* outp = (float*)d_out;              // [64,128,32]
    if (ws_size >= WS_NEED) {
        caps_prep<<<dim3(4160), dim3(512), 0, stream>>>(x, w, (unsigned char*)d_ws);
        caps_main<<<dim3(256), dim3(512), 0, stream>>>((const unsigned char*)d_ws, outp);
    } else {
        caps_route_fb<<<dim3(512), dim3(512), 0, stream>>>(x, w, outp);
    }
}

// Round 3
// 539.223 us; speedup vs baseline: 1.0582x; 1.0094x over previous
//
#include <hip/hip_runtime.h>

// CapsuleLinear dynamic routing via bf16 hi/lo MFMA. N=64, I=256, O=128, K=16, L=32.
//
// Round 13 = R12 (3-buffer rotating prefetch, bench-verified numerics) with
//   the register budget actually granted: __launch_bounds__(512, 2).
//   R12 failed ONLY because hipcc's default budget (128 VGPR at bare
//   launch_bounds(512)) forced a spill (VGPR_Count=128, WRITE_SIZE=545MB).
//   We are grid-pinned at 1 block/CU = 2 waves/SIMD, so up to 256 VGPRs are
//   free; min-waves=2 raises the cap to 256. Pipeline needs ~176.
//   Numerics identical to R10/R12 (hi/lo RNE split, 3-MFMA triple product).

#define ICAPS 256
#define OCAPS 128
#define WS_XC 67108864ull
#define WS_NEED 68157440ull
#define KPAD 20

typedef __attribute__((ext_vector_type(8))) short s16x8;
typedef __attribute__((ext_vector_type(16))) float f32x16;

union u4s8 { unsigned u[4]; s16x8 v; };

__device__ inline unsigned rne_adj(unsigned u) {       // bits + RNE increment
    return u + 0x7FFFu + ((u >> 16) & 1u);
}

// RNE hi/lo split of 8 fp32 -> two packed s16x8 (bf16 pairs), R4/R6 numerics.
__device__ inline void split8(const float* f, s16x8& hi, s16x8& lo) {
    u4s8 H, L;
    #pragma unroll
    for (int c = 0; c < 4; ++c) {
        const unsigned u0 = __float_as_uint(f[2 * c]);
        const unsigned u1 = __float_as_uint(f[2 * c + 1]);
        const unsigned r0 = rne_adj(u0), r1 = rne_adj(u1);
        H.u[c] = __builtin_amdgcn_perm(r1, r0, 0x07060302u);   // {hi16(r1),hi16(r0)}
        const float h0 = __uint_as_float(r0 & 0xFFFF0000u);
        const float h1 = __uint_as_float(r1 & 0xFFFF0000u);
        const unsigned l0 = rne_adj(__float_as_uint(f[2 * c] - h0));      // exact resid
        const unsigned l1 = rne_adj(__float_as_uint(f[2 * c + 1] - h1));  // then RNE
        L.u[c] = __builtin_amdgcn_perm(l1, l0, 0x07060302u);
    }
    hi = H.v; lo = L.v;
}

// ---------------- prep: coalesced read + LDS transpose + split ----------------
// w tiles: gid 0..32767 (= o*256+i); x tiles: gid 32768..33279 (= nh*256+i).
__global__ __launch_bounds__(512)
void caps_prep(const float* __restrict__ x, const float* __restrict__ w,
               unsigned char* __restrict__ ws) {
    __shared__ float T[8][32 * KPAD];     // per-wave 2.5 KB transpose buffer
    const int wv = threadIdx.x >> 6, lane = threadIdx.x & 63;
    const int gid = blockIdx.x * 8 + wv;
    float f[8];
    s16x8 hi, lo;

    if (gid < 32768) {
        // coalesced: wave reads its whole 2KB tile (512 floats) contiguously
        const float* src = w + (size_t)gid * 512 + lane * 8;
        const float4 a = *(const float4*)src;
        const float4 b = *(const float4*)(src + 4);
        const float v[8] = {a.x, a.y, a.z, a.w, b.x, b.y, b.z, b.w};
        // element j: k = lane>>2 (const), l = (lane&3)*8 + j  -> T[l][k]
        {
            float* Tw = &T[wv][0];
            const int k = lane >> 2, l0 = (lane & 3) * 8;
            #pragma unroll
            for (int j = 0; j < 8; ++j) Tw[(l0 + j) * KPAD + k] = v[j];
        }
        // T is strictly per-wave: a wave-local LDS drain suffices (no barrier).
        asm volatile("s_waitcnt lgkmcnt(0)" ::: "memory");
        // fragment read: l = lane&31, k = kb..kb+7 (contiguous -> 2x b128)
        {
            const float* rd = &T[wv][(lane & 31) * KPAD + (lane >> 5) * 8];
            const float4 ra = *(const float4*)rd;
            const float4 rb = *(const float4*)(rd + 4);
            f[0] = ra.x; f[1] = ra.y; f[2] = ra.z; f[3] = ra.w;
            f[4] = rb.x; f[5] = rb.y; f[6] = rb.z; f[7] = rb.w;
        }
        split8(f, hi, lo);
        s16x8* WC = (s16x8*)ws;
        WC[(size_t)gid * 128 + lane] = hi;        // 1KB coalesced
        WC[(size_t)gid * 128 + 64 + lane] = lo;   // 1KB coalesced
    } else if (gid < 33280) {
        const int id = gid - 32768;
        const int nh = id >> 8, i = id & 255;
        const int n = lane & 31, kb = (lane >> 5) * 8;
        const float* src = x + ((size_t)(nh * 32 + n) * ICAPS + i) * 16 + kb;
        const float4 a = *(const float4*)src;
        const float4 b = *(const float4*)(src + 4);
        f[0] = a.x; f[1] = a.y; f[2] = a.z; f[3] = a.w;
        f[4] = b.x; f[5] = b.y; f[6] = b.z; f[7] = b.w;
        split8(f, hi, lo);
        s16x8* XC = (s16x8*)(ws + WS_XC);
        XC[(size_t)id * 128 + lane] = hi;
        XC[(size_t)id * 128 + 64 + lane] = lo;
    }
}

// ---------------- main: MFMA routing, 8 waves, 3-buffer rotating prefetch ----------------

#define MF(a, b, c) __builtin_amdgcn_mfma_f32_32x32x16_bf16(a, b, c, 0, 0, 0)

// load one 2-i batch (8 s16x8 = 32 VGPR) for batch index bb (i = ibase+2*bb)
#define LD8(B, bb)                                        \
    {                                                     \
        const size_t b_ = (size_t)(ibase + 2 * (bb)) * 128; \
        B[0] = Wp[b_];       B[1] = Wp[b_ + 64];          \
        B[2] = Xp[b_];       B[3] = Xp[b_ + 64];          \
        B[4] = Wp[b_ + 128]; B[5] = Wp[b_ + 192];         \
        B[6] = Xp[b_ + 128]; B[7] = Xp[b_ + 192];         \
    }

#define SOFTSTEP(P, ii)                                                   \
    {                                                                     \
        float da = P[0] * vr[0], db = P[8] * vr[8];                       \
        _Pragma("unroll")                                                 \
        for (int r = 1; r < 8; ++r) {                                     \
            da = fmaf(P[r], vr[r], da);                                   \
            db = fmaf(P[r + 8], vr[r + 8], db);                           \
        }                                                                 \
        float d = da + db;                                                \
        d += __shfl_xor(d, 32);                /* combine l-halves */     \
        if (pass == 1) {                                                  \
            if (half == 0) lg[(ii) * 32 + n] = d;                         \
        } else {                                                          \
            d += lg[(ii) * 32 + n];                                       \
        }                                                                 \
        const float e = __expf(d);                                        \
        z += e;                                                           \
        _Pragma("unroll")                                                 \
        for (int r = 0; r < 16; ++r) uacc[r] = fmaf(e, P[r], uacc[r]);    \
    }

__global__ __launch_bounds__(512, 2)
void caps_main(const unsigned char* __restrict__ ws, float* __restrict__ out) {
    __shared__ float lg[ICAPS * 32];      // [i][n] 32 KB
    __shared__ float slab[8 * 1280];      // per-wave u partials (lane stride 20)
    __shared__ float svv[32 * 33];        // s then v
    __shared__ float zz[8 * 32];
    __shared__ float zinv[32];

    const int t = threadIdx.x, wv = t >> 6, lane = t & 63;
    const int o = blockIdx.x & 127, nh = blockIdx.x >> 7;   // o-pairs share an XCD
    const int n = lane & 31, half = lane >> 5;

    // block layout: per tile 128 s16x8 records; hi at +lane, lo at +64+lane
    const s16x8* Wp = (const s16x8*)ws + (size_t)o * ICAPS * 128 + lane;
    const s16x8* Xp = (const s16x8*)(ws + WS_XC) + (size_t)nh * ICAPS * 128 + lane;

    float vr[16];
    const int ibase = wv * 32;            // 32 i per wave, 16 batches of 2

    for (int pass = 0; pass < 3; ++pass) {
        float uacc[16];
        #pragma unroll
        for (int r = 0; r < 16; ++r) uacc[r] = 0.f;
        float z = 0.f;

        // 3-slot rotating batch buffers: 6 i-tiles (24KB/wave) in flight,
        // no register copies, prefetch distance 3 batches. ~176 VGPRs,
        // granted by launch_bounds(512,2) -> cap 256 (we run 2 waves/SIMD).
        s16x8 B[3][8];
        LD8(B[0], 0);
        LD8(B[1], 1);
        LD8(B[2], 2);

        if (pass == 0) {
            f32x16 Pa = {}, Pb = {};
            #pragma unroll
            for (int qq = 0; qq < 16; ++qq) {
                s16x8(&C)[8] = B[qq % 3];             // constant after unroll
                Pa = MF(C[1], C[2], Pa);
                Pb = MF(C[5], C[6], Pb);
                Pa = MF(C[0], C[3], Pa);
                Pb = MF(C[4], C[7], Pb);
                Pa = MF(C[0], C[2], Pa);
                Pb = MF(C[4], C[6], Pb);
                if (qq < 13) LD8(C, qq + 3);
            }
            #pragma unroll
            for (int r = 0; r < 16; ++r) uacc[r] = Pa[r] + Pb[r];
        } else {
            #pragma unroll
            for (int qq = 0; qq < 16; ++qq) {
                s16x8(&C)[8] = B[qq % 3];             // constant after unroll
                f32x16 P0 = {}, P1 = {};
                P0 = MF(C[1], C[2], P0);
                P1 = MF(C[5], C[6], P1);
                P0 = MF(C[0], C[3], P0);
                P1 = MF(C[4], C[7], P1);
                P0 = MF(C[0], C[2], P0);
                P1 = MF(C[4], C[6], P1);
                if (qq < 13) LD8(C, qq + 3);          // loads hide under softmax
                SOFTSTEP(P0, ibase + 2 * qq);
                SOFTSTEP(P1, ibase + 2 * qq + 1);
            }
        }

        // ---- cross-wave reduce of u (and z) over 8 waves ----
        #pragma unroll
        for (int c = 0; c < 4; ++c)
            *(float4*)(&slab[wv * 1280 + lane * 20 + c * 4]) =
                make_float4(uacc[4 * c], uacc[4 * c + 1], uacc[4 * c + 2], uacc[4 * c + 3]);
        if (pass > 0 && half == 0) zz[wv * 32 + n] = z;
        __syncthreads();

        #pragma unroll
        for (int hh = 0; hh < 2; ++hh) {
            const int e = t + hh * 512;
            const int lw = e >> 4, r = e & 15;
            float s = 0.f;
            #pragma unroll
            for (int w8 = 0; w8 < 8; ++w8) s += slab[w8 * 1280 + lw * 20 + r];
            const int nn = lw & 31, ll = (r & 3) + 8 * (r >> 2) + 4 * (lw >> 5);
            svv[nn * 33 + ll] = s;
        }
        if (t < 32) {
            if (pass == 0) zinv[t] = 1.0f / 256.0f;
            else {
                float zs = 0.f;
                #pragma unroll
                for (int w8 = 0; w8 < 8; ++w8) zs += zz[w8 * 32 + t];
                zinv[t] = 1.0f / zs;
            }
        }
        __syncthreads();

        // ---- squash (and output on last pass) ----
        {
            const int nq = t >> 4, sub = t & 15;
            const float a = svv[nq * 33 + sub] * zinv[nq];
            const float b = svv[nq * 33 + sub + 16] * zinv[nq];
            float sq = a * a + b * b;
            #pragma unroll
            for (int m = 1; m < 16; m <<= 1) sq += __shfl_xor(sq, m, 16);
            const float sc = sqrtf(sq) / (1.0f + sq);
            if (pass == 2) {
                const int ng = nh * 32 + nq;
                out[((size_t)ng * OCAPS + o) * 32 + sub] = a * sc;
                out[((size_t)ng * OCAPS + o) * 32 + sub + 16] = b * sc;
            } else {
                svv[nq * 33 + sub] = a * sc;
                svv[nq * 33 + sub + 16] = b * sc;
            }
        }
        if (pass < 2) {
            __syncthreads();
            #pragma unroll
            for (int r = 0; r < 16; ++r) {
                const int l = (r & 3) + 8 * (r >> 2) + 4 * half;
                vr[r] = svv[n * 33 + l];
            }
        }
    }
}

// ---------------- fallback (round-3 kernel, no ws needed) ----------------
#define KLEN  16
#define LLEN  32
#define TN    16
#define LGS   257
#define XROW  20
#define XIST  (TN * XROW + 4)
#define SVS   33
#define RBS   33
#define NSTG  32
#define NSTEP (ICAPS / NSTG)

__global__ __launch_bounds__(512, 2)
void caps_route_fb(const float* __restrict__ xg_all,
                   const float* __restrict__ wg_all,
                   float* __restrict__ out) {
    __shared__ float lg[TN * LGS];
    __shared__ float xt[NSTG * XIST];
    __shared__ float sv[TN * SVS];
    __shared__ float zz[8][TN];
    __shared__ float zinv[TN];

    const int t   = threadIdx.x;
    const int o   = blockIdx.x & 127;
    const int n0  = (blockIdx.x >> 7) * TN;
    const int isp = t >> 4;
    const int lb  = (t >> 2) & 3;
    const int nb  = t & 3;
    const int l0  = lb * 8;

    const float* xg = xg_all + (size_t)n0 * ICAPS * KLEN;
    const float* wg = wg_all + (size_t)o * ICAPS * KLEN * LLEN;

    for (int pass = 0; pass < 3; ++pass) {
        float u[4][8];
        float zq[4] = {0.f, 0.f, 0.f, 0.f};
        #pragma unroll
        for (int q = 0; q < 4; ++q)
            #pragma unroll
            for (int r = 0; r < 8; ++r) u[q][r] = 0.f;

        for (int st = 0; st < NSTEP; ++st) {
            const int i0 = st * NSTG;
            __syncthreads();
            #pragma unroll
            for (int j = 0; j < 4; ++j) {
                const int g   = j * 512 + t;
                const int nn  = g >> 7;
                const int rem = g & 127;
                const int il  = rem >> 2;
                const int k4c = rem & 3;
                *(float4*)(&xt[il * XIST + nn * XROW + k4c * 4]) =
                    *(const float4*)(xg + (size_t)(nn * ICAPS + i0 + il) * KLEN + k4c * 4);
            }
            __syncthreads();

            const int i = i0 + isp;
            const float* wp = wg + (size_t)i * (KLEN * LLEN) + l0;
            const float* xp = &xt[isp * XIST];
            float P[4][8];
            #pragma unroll
            for (int q = 0; q < 4; ++q)
                #pragma unroll
                for (int r = 0; r < 8; ++r) P[q][r] = 0.f;

            #pragma unroll
            for (int k4 = 0; k4 < 4; ++k4) {
                float xq[4][4];
                #pragma unroll
                for (int q = 0; q < 4; ++q)
                    *(float4*)(&xq[q][0]) = *(const float4*)(xp + (nb + 4 * q) * XROW + k4 * 4);
                #pragma unroll
                for (int kk = 0; kk < 4; ++kk) {
                    const int k = k4 * 4 + kk;
                    const float4 wa = *(const float4*)(wp + k * LLEN);
                    const float4 wb = *(const float4*)(wp + k * LLEN + 4);
                    #pragma unroll
                    for (int q = 0; q < 4; ++q) {
                        const float xv = xq[q][kk];
                        P[q][0] = fmaf(xv, wa.x, P[q][0]);
                        P[q][1] = fmaf(xv, wa.y, P[q][1]);
                        P[q][2] = fmaf(xv, wa.z, P[q][2]);
                        P[q][3] = fmaf(xv, wa.w, P[q][3]);
                        P[q][4] = fmaf(xv, wb.x, P[q][4]);
                        P[q][5] = fmaf(xv, wb.y, P[q][5]);
                        P[q][6] = fmaf(xv, wb.z, P[q][6]);
                        P[q][7] = fmaf(xv, wb.w, P[q][7]);
                    }
                }
            }

            if (pass == 0) {
                #pragma unroll
                for (int q = 0; q < 4; ++q)
                    #pragma unroll
                    for (int r = 0; r < 8; ++r) u[q][r] += P[q][r];
            } else {
                #pragma unroll
                for (int q = 0; q < 4; ++q) {
                    const float* vp = &sv[(nb + 4 * q) * SVS + l0];
                    float d = P[q][0] * vp[0] + P[q][1] * vp[1] + P[q][2] * vp[2] + P[q][3] * vp[3]
                            + P[q][4] * vp[4] + P[q][5] * vp[5] + P[q][6] * vp[6] + P[q][7] * vp[7];
                    d += __shfl_xor(d, 4);
                    d += __shfl_xor(d, 8);
                    float lnew = d;
                    if (pass == 2) lnew += lg[(nb + 4 * q) * LGS + i];
                    else if (lb == 0) lg[(nb + 4 * q) * LGS + i] = lnew;
                    const float e = __expf(lnew);
                    zq[q] += e;
                    #pragma unroll
                    for (int r = 0; r < 8; ++r) u[q][r] = fmaf(e, P[q][r], u[q][r]);
                }
            }
        }

        #pragma unroll
        for (int q = 0; q < 4; ++q) {
            #pragma unroll
            for (int r = 0; r < 8; ++r) {
                float v = u[q][r];
                v += __shfl_xor(v, 16);
                v += __shfl_xor(v, 32);
                u[q][r] = v;
            }
            float zv = zq[q];
            zv += __shfl_xor(zv, 16);
            zv += __shfl_xor(zv, 32);
            zq[q] = zv;
        }
        __syncthreads();
        {
            const int wvv = t >> 6, lane = t & 63;
            if (lane < 16) {
                float* rb = &xt[wvv * (16 * RBS) + lane * RBS];
                #pragma unroll
                for (int q = 0; q < 4; ++q)
                    #pragma unroll
                    for (int r = 0; r < 8; ++r) rb[q * 8 + r] = u[q][r];
            }
            if (pass > 0 && lane < 4) {
                #pragma unroll
                for (int q = 0; q < 4; ++q) zz[wvv][lane + 4 * q] = zq[q];
            }
        }
        __syncthreads();
        {
            const int low4 = t >> 5, qr = t & 31;
            const int qq = qr >> 3, rr = qr & 7;
            const int lbb = low4 >> 2, nbb = low4 & 3;
            float ssum = 0.f;
            #pragma unroll
            for (int w8 = 0; w8 < 8; ++w8) ssum += xt[w8 * (16 * RBS) + low4 * RBS + qr];
            sv[(nbb + 4 * qq) * SVS + lbb * 8 + rr] = ssum;
        }
        if (t < TN) {
            if (pass == 0) zinv[t] = 1.0f / 256.0f;
            else {
                float zs = 0.f;
                #pragma unroll
                for (int w8 = 0; w8 < 8; ++w8) zs += zz[w8][t];
                zinv[t] = 1.0f / zs;
            }
        }
        __syncthreads();
        {
            const int nn = t >> 5, l = t & 31;
            const float val = sv[nn * SVS + l] * zinv[nn];
            float sq = val * val;
            #pragma unroll
            for (int m = 1; m < 32; m <<= 1) sq += __shfl_xor(sq, m, 32);
            const float sc = sqrtf(sq) / (1.0f + sq);
            if (pass == 2)
                out[((size_t)(n0 + nn) * OCAPS + o) * LLEN + l] = val * sc;
            else
                sv[nn * SVS + l] = val * sc;
        }
    }
}

extern "C" void kernel_launch(void* const* d_in, const int* in_sizes, int n_in,
                              void* d_out, int out_size, void* d_ws, size_t ws_size,
                              hipStream_t stream) {
    const float* x = (const float*)d_in[0];   // [64,256,16]
    const float* w = (const float*)d_in[1];   // [128,256,16,32]
    float* outp = (float*)d_out;              // [64,128,32]
    if (ws_size >= WS_NEED) {
        caps_prep<<<dim3(4160), dim3(512), 0, stream>>>(x, w, (unsigned char*)d_ws);
        caps_main<<<dim3(256), dim3(512), 0, stream>>>((const unsigned char*)d_ws, outp);
    } else {
        caps_route_fb<<<dim3(512), dim3(512), 0, stream>>>(x, w, outp);
    }
}

// Round 4
// 219.542 us; speedup vs baseline: 2.5990x; 2.4561x over previous
//
#include <hip/hip_runtime.h>

// CapsuleLinear dynamic routing via bf16 hi/lo MFMA. N=64, I=256, O=128, K=16, L=32.
//
// Round 14 = R10's proven numerics + deep prefetch with ONLY named registers.
//   R12/R13 failed because s16x8 B[3][8] indexed by qq%3 was demoted to
//   scratch (rule: runtime-indexed ext_vector arrays -> local memory; the
//   demotion happens before unroll constant-folds the index), giving
//   VGPR=128 + 545MB scratch writes regardless of launch_bounds.
//   Now: rotation unit = ONE i-tile (4 s16x8 records, 16 VGPRs) across four
//   individually NAMED buffers FA/FB/FC/FD, grouped 4 steps per iteration
//   (32 steps, no tail). Prefetch for step i+4 issues at step i ->
//   distance 3 compute steps (~500-700cy) ~ LLC latency. ~115 VGPRs total.
//   Next-pass prologue loads issue before the reduction phase (overlap).
//   FP accumulation order identical to R10 (even i -> Pa, odd -> Pb).

#define ICAPS 256
#define OCAPS 128
#define WS_XC 67108864ull
#define WS_NEED 68157440ull
#define KPAD 20

typedef __attribute__((ext_vector_type(8))) short s16x8;
typedef __attribute__((ext_vector_type(16))) float f32x16;

union u4s8 { unsigned u[4]; s16x8 v; };

__device__ inline unsigned rne_adj(unsigned u) {       // bits + RNE increment
    return u + 0x7FFFu + ((u >> 16) & 1u);
}

// RNE hi/lo split of 8 fp32 -> two packed s16x8 (bf16 pairs), R4/R6 numerics.
__device__ inline void split8(const float* f, s16x8& hi, s16x8& lo) {
    u4s8 H, L;
    #pragma unroll
    for (int c = 0; c < 4; ++c) {
        const unsigned u0 = __float_as_uint(f[2 * c]);
        const unsigned u1 = __float_as_uint(f[2 * c + 1]);
        const unsigned r0 = rne_adj(u0), r1 = rne_adj(u1);
        H.u[c] = __builtin_amdgcn_perm(r1, r0, 0x07060302u);   // {hi16(r1),hi16(r0)}
        const float h0 = __uint_as_float(r0 & 0xFFFF0000u);
        const float h1 = __uint_as_float(r1 & 0xFFFF0000u);
        const unsigned l0 = rne_adj(__float_as_uint(f[2 * c] - h0));      // exact resid
        const unsigned l1 = rne_adj(__float_as_uint(f[2 * c + 1] - h1));  // then RNE
        L.u[c] = __builtin_amdgcn_perm(l1, l0, 0x07060302u);
    }
    hi = H.v; lo = L.v;
}

// ---------------- prep: coalesced read + LDS transpose + split ----------------
// w tiles: gid 0..32767 (= o*256+i); x tiles: gid 32768..33279 (= nh*256+i).
__global__ __launch_bounds__(512)
void caps_prep(const float* __restrict__ x, const float* __restrict__ w,
               unsigned char* __restrict__ ws) {
    __shared__ float T[8][32 * KPAD];     // per-wave 2.5 KB transpose buffer
    const int wv = threadIdx.x >> 6, lane = threadIdx.x & 63;
    const int gid = blockIdx.x * 8 + wv;
    float f[8];
    s16x8 hi, lo;

    if (gid < 32768) {
        // coalesced: wave reads its whole 2KB tile (512 floats) contiguously
        const float* src = w + (size_t)gid * 512 + lane * 8;
        const float4 a = *(const float4*)src;
        const float4 b = *(const float4*)(src + 4);
        const float v[8] = {a.x, a.y, a.z, a.w, b.x, b.y, b.z, b.w};
        // element j: k = lane>>2 (const), l = (lane&3)*8 + j  -> T[l][k]
        {
            float* Tw = &T[wv][0];
            const int k = lane >> 2, l0 = (lane & 3) * 8;
            #pragma unroll
            for (int j = 0; j < 8; ++j) Tw[(l0 + j) * KPAD + k] = v[j];
        }
        // T is strictly per-wave: a wave-local LDS drain suffices (no barrier).
        asm volatile("s_waitcnt lgkmcnt(0)" ::: "memory");
        // fragment read: l = lane&31, k = kb..kb+7 (contiguous -> 2x b128)
        {
            const float* rd = &T[wv][(lane & 31) * KPAD + (lane >> 5) * 8];
            const float4 ra = *(const float4*)rd;
            const float4 rb = *(const float4*)(rd + 4);
            f[0] = ra.x; f[1] = ra.y; f[2] = ra.z; f[3] = ra.w;
            f[4] = rb.x; f[5] = rb.y; f[6] = rb.z; f[7] = rb.w;
        }
        split8(f, hi, lo);
        s16x8* WC = (s16x8*)ws;
        WC[(size_t)gid * 128 + lane] = hi;        // 1KB coalesced
        WC[(size_t)gid * 128 + 64 + lane] = lo;   // 1KB coalesced
    } else if (gid < 33280) {
        const int id = gid - 32768;
        const int nh = id >> 8, i = id & 255;
        const int n = lane & 31, kb = (lane >> 5) * 8;
        const float* src = x + ((size_t)(nh * 32 + n) * ICAPS + i) * 16 + kb;
        const float4 a = *(const float4*)src;
        const float4 b = *(const float4*)(src + 4);
        f[0] = a.x; f[1] = a.y; f[2] = a.z; f[3] = a.w;
        f[4] = b.x; f[5] = b.y; f[6] = b.z; f[7] = b.w;
        split8(f, hi, lo);
        s16x8* XC = (s16x8*)(ws + WS_XC);
        XC[(size_t)id * 128 + lane] = hi;
        XC[(size_t)id * 128 + 64 + lane] = lo;
    }
}

// ---------------- main: MFMA routing, 8 waves, 4-named-buffer rotation ----------------

#define MF(a, b, c) __builtin_amdgcn_mfma_f32_32x32x16_bf16(a, b, c, 0, 0, 0)

// load ONE i-tile (4 s16x8 records = 16 VGPRs) into named regs N0..N3.
// N0 = W hi, N1 = W lo, N2 = X hi, N3 = X lo.
#define LD1(N, ii)                                   \
    {                                                \
        const size_t b_ = (size_t)(ii) * 128;        \
        N##0 = Wp[b_]; N##1 = Wp[b_ + 64];           \
        N##2 = Xp[b_]; N##3 = Xp[b_ + 64];           \
    }

// 3-MFMA triple product for one i (order identical to R10: al*bh, ah*bl, ah*bh)
#define TRIP(N, ACC)                 \
    {                                \
        ACC = MF(N##1, N##2, ACC);   \
        ACC = MF(N##0, N##3, ACC);   \
        ACC = MF(N##0, N##2, ACC);   \
    }

#define SOFTSTEP(P, ii)                                                   \
    {                                                                     \
        float da = P[0] * vr[0], db = P[8] * vr[8];                       \
        _Pragma("unroll")                                                 \
        for (int r = 1; r < 8; ++r) {                                     \
            da = fmaf(P[r], vr[r], da);                                   \
            db = fmaf(P[r + 8], vr[r + 8], db);                           \
        }                                                                 \
        float d = da + db;                                                \
        d += __shfl_xor(d, 32);                /* combine l-halves */     \
        if (pass == 1) {                                                  \
            if (half == 0) lg[(ii) * 32 + n] = d;                         \
        } else {                                                          \
            d += lg[(ii) * 32 + n];                                       \
        }                                                                 \
        const float e = __expf(d);                                        \
        z += e;                                                           \
        _Pragma("unroll")                                                 \
        for (int r = 0; r < 16; ++r) uacc[r] = fmaf(e, P[r], uacc[r]);    \
    }

// one pass>=1 step: fresh P, triple product, softmax-accumulate
#define PROC1(N, ii)                 \
    {                                \
        f32x16 P = {};               \
        TRIP(N, P);                  \
        SOFTSTEP(P, ii);             \
    }

__global__ __launch_bounds__(512)
void caps_main(const unsigned char* __restrict__ ws, float* __restrict__ out) {
    __shared__ float lg[ICAPS * 32];      // [i][n] 32 KB
    __shared__ float slab[8 * 1280];      // per-wave u partials (lane stride 20)
    __shared__ float svv[32 * 33];        // s then v
    __shared__ float zz[8 * 32];
    __shared__ float zinv[32];

    const int t = threadIdx.x, wv = t >> 6, lane = t & 63;
    const int o = blockIdx.x & 127, nh = blockIdx.x >> 7;   // o-pairs share an XCD
    const int n = lane & 31, half = lane >> 5;

    // block layout: per tile 128 s16x8 records; hi at +lane, lo at +64+lane
    const s16x8* Wp = (const s16x8*)ws + (size_t)o * ICAPS * 128 + lane;
    const s16x8* Xp = (const s16x8*)(ws + WS_XC) + (size_t)nh * ICAPS * 128 + lane;

    float vr[16];
    const int ibase = wv * 32;            // 32 i per wave = 32 steps of 1 i-tile

    // four individually-NAMED rotation buffers (16 VGPRs each; never
    // array-indexed -> guaranteed register allocation, no scratch)
    s16x8 FA0, FA1, FA2, FA3;
    s16x8 FB0, FB1, FB2, FB3;
    s16x8 FC0, FC1, FC2, FC3;
    s16x8 FD0, FD1, FD2, FD3;

    // prologue for pass 0 (subsequent passes prefetch before the reduction)
    LD1(FA, ibase + 0);
    LD1(FB, ibase + 1);
    LD1(FC, ibase + 2);
    LD1(FD, ibase + 3);

    for (int pass = 0; pass < 3; ++pass) {
        float uacc[16];
        #pragma unroll
        for (int r = 0; r < 16; ++r) uacc[r] = 0.f;
        float z = 0.f;

        if (pass == 0) {
            f32x16 Pa = {}, Pb = {};
            for (int gq = 0; gq < 8; ++gq) {
                const int iq = ibase + gq * 4;
                if (gq < 7) {
                    TRIP(FA, Pa); LD1(FA, iq + 4);
                    TRIP(FB, Pb); LD1(FB, iq + 5);
                    TRIP(FC, Pa); LD1(FC, iq + 6);
                    TRIP(FD, Pb); LD1(FD, iq + 7);
                } else {
                    TRIP(FA, Pa);
                    TRIP(FB, Pb);
                    TRIP(FC, Pa);
                    TRIP(FD, Pb);
                }
            }
            #pragma unroll
            for (int r = 0; r < 16; ++r) uacc[r] = Pa[r] + Pb[r];
        } else {
            for (int gq = 0; gq < 8; ++gq) {
                const int iq = ibase + gq * 4;
                if (gq < 7) {
                    PROC1(FA, iq + 0); LD1(FA, iq + 4);
                    PROC1(FB, iq + 1); LD1(FB, iq + 5);
                    PROC1(FC, iq + 2); LD1(FC, iq + 6);
                    PROC1(FD, iq + 3); LD1(FD, iq + 7);
                } else {
                    PROC1(FA, iq + 0);
                    PROC1(FB, iq + 1);
                    PROC1(FC, iq + 2);
                    PROC1(FD, iq + 3);
                }
            }
        }

        // prefetch next pass's first 4 i-tiles NOW -> latency hides under
        // the block-wide reduction/squash phase below
        if (pass < 2) {
            LD1(FA, ibase + 0);
            LD1(FB, ibase + 1);
            LD1(FC, ibase + 2);
            LD1(FD, ibase + 3);
        }

        // ---- cross-wave reduce of u (and z) over 8 waves ----
        #pragma unroll
        for (int c = 0; c < 4; ++c)
            *(float4*)(&slab[wv * 1280 + lane * 20 + c * 4]) =
                make_float4(uacc[4 * c], uacc[4 * c + 1], uacc[4 * c + 2], uacc[4 * c + 3]);
        if (pass > 0 && half == 0) zz[wv * 32 + n] = z;
        __syncthreads();

        #pragma unroll
        for (int hh = 0; hh < 2; ++hh) {
            const int e = t + hh * 512;
            const int lw = e >> 4, r = e & 15;
            float s = 0.f;
            #pragma unroll
            for (int w8 = 0; w8 < 8; ++w8) s += slab[w8 * 1280 + lw * 20 + r];
            const int nn = lw & 31, ll = (r & 3) + 8 * (r >> 2) + 4 * (lw >> 5);
            svv[nn * 33 + ll] = s;
        }
        if (t < 32) {
            if (pass == 0) zinv[t] = 1.0f / 256.0f;
            else {
                float zs = 0.f;
                #pragma unroll
                for (int w8 = 0; w8 < 8; ++w8) zs += zz[w8 * 32 + t];
                zinv[t] = 1.0f / zs;
            }
        }
        __syncthreads();

        // ---- squash (and output on last pass) ----
        {
            const int nq = t >> 4, sub = t & 15;
            const float a = svv[nq * 33 + sub] * zinv[nq];
            const float b = svv[nq * 33 + sub + 16] * zinv[nq];
            float sq = a * a + b * b;
            #pragma unroll
            for (int m = 1; m < 16; m <<= 1) sq += __shfl_xor(sq, m, 16);
            const float sc = sqrtf(sq) / (1.0f + sq);
            if (pass == 2) {
                const int ng = nh * 32 + nq;
                out[((size_t)ng * OCAPS + o) * 32 + sub] = a * sc;
                out[((size_t)ng * OCAPS + o) * 32 + sub + 16] = b * sc;
            } else {
                svv[nq * 33 + sub] = a * sc;
                svv[nq * 33 + sub + 16] = b * sc;
            }
        }
        if (pass < 2) {
            __syncthreads();
            #pragma unroll
            for (int r = 0; r < 16; ++r) {
                const int l = (r & 3) + 8 * (r >> 2) + 4 * half;
                vr[r] = svv[n * 33 + l];
            }
        }
    }
}

// ---------------- fallback (round-3 kernel, no ws needed) ----------------
#define KLEN  16
#define LLEN  32
#define TN    16
#define LGS   257
#define XROW  20
#define XIST  (TN * XROW + 4)
#define SVS   33
#define RBS   33
#define NSTG  32
#define NSTEP (ICAPS / NSTG)

__global__ __launch_bounds__(512, 2)
void caps_route_fb(const float* __restrict__ xg_all,
                   const float* __restrict__ wg_all,
                   float* __restrict__ out) {
    __shared__ float lg[TN * LGS];
    __shared__ float xt[NSTG * XIST];
    __shared__ float sv[TN * SVS];
    __shared__ float zz[8][TN];
    __shared__ float zinv[TN];

    const int t   = threadIdx.x;
    const int o   = blockIdx.x & 127;
    const int n0  = (blockIdx.x >> 7) * TN;
    const int isp = t >> 4;
    const int lb  = (t >> 2) & 3;
    const int nb  = t & 3;
    const int l0  = lb * 8;

    const float* xg = xg_all + (size_t)n0 * ICAPS * KLEN;
    const float* wg = wg_all + (size_t)o * ICAPS * KLEN * LLEN;

    for (int pass = 0; pass < 3; ++pass) {
        float u[4][8];
        float zq[4] = {0.f, 0.f, 0.f, 0.f};
        #pragma unroll
        for (int q = 0; q < 4; ++q)
            #pragma unroll
            for (int r = 0; r < 8; ++r) u[q][r] = 0.f;

        for (int st = 0; st < NSTEP; ++st) {
            const int i0 = st * NSTG;
            __syncthreads();
            #pragma unroll
            for (int j = 0; j < 4; ++j) {
                const int g   = j * 512 + t;
                const int nn  = g >> 7;
                const int rem = g & 127;
                const int il  = rem >> 2;
                const int k4c = rem & 3;
                *(float4*)(&xt[il * XIST + nn * XROW + k4c * 4]) =
                    *(const float4*)(xg + (size_t)(nn * ICAPS + i0 + il) * KLEN + k4c * 4);
            }
            __syncthreads();

            const int i = i0 + isp;
            const float* wp = wg + (size_t)i * (KLEN * LLEN) + l0;
            const float* xp = &xt[isp * XIST];
            float P[4][8];
            #pragma unroll
            for (int q = 0; q < 4; ++q)
                #pragma unroll
                for (int r = 0; r < 8; ++r) P[q][r] = 0.f;

            #pragma unroll
            for (int k4 = 0; k4 < 4; ++k4) {
                float xq[4][4];
                #pragma unroll
                for (int q = 0; q < 4; ++q)
                    *(float4*)(&xq[q][0]) = *(const float4*)(xp + (nb + 4 * q) * XROW + k4 * 4);
                #pragma unroll
                for (int kk = 0; kk < 4; ++kk) {
                    const int k = k4 * 4 + kk;
                    const float4 wa = *(const float4*)(wp + k * LLEN);
                    const float4 wb = *(const float4*)(wp + k * LLEN + 4);
                    #pragma unroll
                    for (int q = 0; q < 4; ++q) {
                        const float xv = xq[q][kk];
                        P[q][0] = fmaf(xv, wa.x, P[q][0]);
                        P[q][1] = fmaf(xv, wa.y, P[q][1]);
                        P[q][2] = fmaf(xv, wa.z, P[q][2]);
                        P[q][3] = fmaf(xv, wa.w, P[q][3]);
                        P[q][4] = fmaf(xv, wb.x, P[q][4]);
                        P[q][5] = fmaf(xv, wb.y, P[q][5]);
                        P[q][6] = fmaf(xv, wb.z, P[q][6]);
                        P[q][7] = fmaf(xv, wb.w, P[q][7]);
                    }
                }
            }

            if (pass == 0) {
                #pragma unroll
                for (int q = 0; q < 4; ++q)
                    #pragma unroll
                    for (int r = 0; r < 8; ++r) u[q][r] += P[q][r];
            } else {
                #pragma unroll
                for (int q = 0; q < 4; ++q) {
                    const float* vp = &sv[(nb + 4 * q) * SVS + l0];
                    float d = P[q][0] * vp[0] + P[q][1] * vp[1] + P[q][2] * vp[2] + P[q][3] * vp[3]
                            + P[q][4] * vp[4] + P[q][5] * vp[5] + P[q][6] * vp[6] + P[q][7] * vp[7];
                    d += __shfl_xor(d, 4);
                    d += __shfl_xor(d, 8);
                    float lnew = d;
                    if (pass == 2) lnew += lg[(nb + 4 * q) * LGS + i];
                    else if (lb == 0) lg[(nb + 4 * q) * LGS + i] = lnew;
                    const float e = __expf(lnew);
                    zq[q] += e;
                    #pragma unroll
                    for (int r = 0; r < 8; ++r) u[q][r] = fmaf(e, P[q][r], u[q][r]);
                }
            }
        }

        #pragma unroll
        for (int q = 0; q < 4; ++q) {
            #pragma unroll
            for (int r = 0; r < 8; ++r) {
                float v = u[q][r];
                v += __shfl_xor(v, 16);
                v += __shfl_xor(v, 32);
                u[q][r] = v;
            }
            float zv = zq[q];
            zv += __shfl_xor(zv, 16);
            zv += __shfl_xor(zv, 32);
            zq[q] = zv;
        }
        __syncthreads();
        {
            const int wvv = t >> 6, lane = t & 63;
            if (lane < 16) {
                float* rb = &xt[wvv * (16 * RBS) + lane * RBS];
                #pragma unroll
                for (int q = 0; q < 4; ++q)
                    #pragma unroll
                    for (int r = 0; r < 8; ++r) rb[q * 8 + r] = u[q][r];
            }
            if (pass > 0 && lane < 4) {
                #pragma unroll
                for (int q = 0; q < 4; ++q) zz[wvv][lane + 4 * q] = zq[q];
            }
        }
        __syncthreads();
        {
            const int low4 = t >> 5, qr = t & 31;
            const int qq = qr >> 3, rr = qr & 7;
            const int lbb = low4 >> 2, nbb = low4 & 3;
            float ssum = 0.f;
            #pragma unroll
            for (int w8 = 0; w8 < 8; ++w8) ssum += xt[w8 * (16 * RBS) + low4 * RBS + qr];
            sv[(nbb + 4 * qq) * SVS + lbb * 8 + rr] = ssum;
        }
        if (t < TN) {
            if (pass == 0) zinv[t] = 1.0f / 256.0f;
            else {
                float zs = 0.f;
                #pragma unroll
                for (int w8 = 0; w8 < 8; ++w8) zs += zz[w8][t];
                zinv[t] = 1.0f / zs;
            }
        }
        __syncthreads();
        {
            const int nn = t >> 5, l = t & 31;
            const float val = sv[nn * SVS + l] * zinv[nn];
            float sq = val * val;
            #pragma unroll
            for (int m = 1; m < 32; m <<= 1) sq += __shfl_xor(sq, m, 32);
            const float sc = sqrtf(sq) / (1.0f + sq);
            if (pass == 2)
                out[((size_t)(n0 + nn) * OCAPS + o) * LLEN + l] = val * sc;
            else
                sv[nn * SVS + l] = val * sc;
        }
    }
}

extern "C" void kernel_launch(void* const* d_in, const int* in_sizes, int n_in,
                              void* d_out, int out_size, void* d_ws, size_t ws_size,
                              hipStream_t stream) {
    const float* x = (const float*)d_in[0];   // [64,256,16]
    const float* w = (const float*)d_in[1];   // [128,256,16,32]
    float* outp = (float*)d_out;              // [64,128,32]
    if (ws_size >= WS_NEED) {
        caps_prep<<<dim3(4160), dim3(512), 0, stream>>>(x, w, (unsigned char*)d_ws);
        caps_main<<<dim3(256), dim3(512), 0, stream>>>((const unsigned char*)d_ws, outp);
    } else {
        caps_route_fb<<<dim3(512), dim3(512), 0, stream>>>(x, w, outp);
    }
}